// Round 2
// baseline (10071.809 us; speedup 1.0000x reference)
//
#include <hip/hip_runtime.h>
#include <cstdint>
#include <cstddef>

#define N_NODES 100000
#define N_EDGES 1600000
// n_in = n_out = 32; edge MLP: 96 -> 96 -> 129; out MLPs: 160 -> 32

// ---- workspace layout (element offsets, 4B elements) ----
#define O_S1   0u         // float [N_NODES*32]  segment sum f1
#define O_M4S  3200000u   // float [N_NODES*32]  segment sum f4
#define O_M2K  6400000u   // uint  [N_NODES*32]  ordered-key max f2 (init 0)
#define O_DEG  9600000u   // uint  [N_NODES]     in-degree (init 0)
#define O_M3K  9700000u   // uint  [N_NODES*32]  ordered-key min f3 (init 0xFFFFFFFF)
#define O_WC   12900000u  // float [96*32]       Wm2[:,1:] @ We[0:128]
#define O_C0   12903072u  // float [32]          bm2[1:]  @ We[0:128]
#define WS_ELEMS 12903104u
#define WS_BYTES ((size_t)WS_ELEMS * 4u)

// order-preserving float<->uint key: key monotone increasing with float value.
// min real-float key = key(-inf) = 0x007FFFFF > 0, so init 0 is a safe identity
// for max; 0xFFFFFFFF is a safe identity for min. Decoded only when deg>0.
__device__ __forceinline__ unsigned fkey(float v){
  unsigned b = __float_as_uint(v);
  return (b & 0x80000000u) ? ~b : (b | 0x80000000u);
}
__device__ __forceinline__ float fdec(unsigned u){
  unsigned b = (u & 0x80000000u) ? (u & 0x7fffffffu) : ~u;
  return __uint_as_float(b);
}

// acc[j] += xv * w[j], j unrolled so acc stays in VGPRs; w uniform -> scalar loads
template<int NJ>
__device__ __forceinline__ void accN(float xv, const float* __restrict__ w, float* acc){
  #pragma unroll
  for (int j = 0; j < NJ; j++) acc[j] = fmaf(xv, w[j], acc[j]);
}

// ---- precompute Wc = Wm2[:,1:129] @ We[0:128,:]  and  c0 = bm2[1:129] @ We[0:128,:] ----
__global__ __launch_bounds__(256) void gsmp_make_wc(
    const float* __restrict__ Wm2, const float* __restrict__ bm2,
    const float* __restrict__ We, float* __restrict__ ws)
{
  int t = blockIdx.x * 256 + threadIdx.x;
  float* Wc = ws + O_WC;
  float* c0 = ws + O_C0;
  if (t < 96 * 32) {
    int k = t >> 5, j = t & 31;
    float s = 0.f;
    for (int i = 0; i < 128; i++) s = fmaf(Wm2[k * 129 + 1 + i], We[i * 32 + j], s);
    Wc[t] = s;
  } else if (t < 96 * 32 + 32) {
    int j = t - 96 * 32;
    float s = 0.f;
    for (int i = 0; i < 128; i++) s = fmaf(bm2[1 + i], We[i * 32 + j], s);
    c0[j] = s;
  }
}

// ---- edge kernel: MLP + gate, scatter atomics, fused out_ve ----
#define EB 128
__global__ __launch_bounds__(EB) void gsmp_edge_kernel(
    const float* __restrict__ in_vc, const float* __restrict__ in_ve,
    const int* __restrict__ src, const int* __restrict__ dst,
    const float* __restrict__ Wm1, const float* __restrict__ bm1,
    const float* __restrict__ Wm2, const float* __restrict__ bm2,
    const float* __restrict__ We, const float* __restrict__ be,
    float* __restrict__ ws, float* __restrict__ out_ve)
{
  // per-thread private h row in LDS; stride 100 floats keeps 16B alignment for
  // ds_read_b128 and gives bank (tid*100+4k)%32 = 4(tid+k)%32 -> 2-way (free).
  __shared__ float hlds[EB * 100];
  int e = blockIdx.x * EB + threadIdx.x;
  bool act = e < N_EDGES;
  int e0 = act ? e : 0;
  int sn = src[e0] * 32;
  int dn = dst[e0] * 32;
  size_t eoff = (size_t)e0 * 32;

  // ---- stage 1: h = relu(concat(vc[src], vc[dst], ve) @ Wm1 + bm1) ----
  float h[96];
  #pragma unroll
  for (int j = 0; j < 96; j++) h[j] = bm1[j];

  const float* base0 = in_vc + sn;
  const float* base1 = in_vc + dn;
  const float* base2 = in_ve + eoff;
  #pragma unroll
  for (int r = 0; r < 3; r++) {
    const float* bp = (r == 0) ? base0 : (r == 1) ? base1 : base2;
    const float4* p4 = (const float4*)bp;
    for (int kc = 0; kc < 8; kc++) {            // rolled: 1 float4 load feeds 384 FMA
      float4 xq = p4[kc];
      const float* w = Wm1 + (r * 32 + kc * 4) * 96;
      accN<96>(xq.x, w + 0 * 96, h);
      accN<96>(xq.y, w + 1 * 96, h);
      accN<96>(xq.z, w + 2 * 96, h);
      accN<96>(xq.w, w + 3 * 96, h);
    }
  }
  float* myh = hlds + threadIdx.x * 100;
  #pragma unroll
  for (int j = 0; j < 96; j += 4) {
    float4 v;
    v.x = fmaxf(h[j + 0], 0.f); v.y = fmaxf(h[j + 1], 0.f);
    v.z = fmaxf(h[j + 2], 0.f); v.w = fmaxf(h[j + 3], 0.f);
    *(float4*)(myh + j) = v;
  }
  // no __syncthreads: each thread touches only its own LDS row

  // ---- gate: y0 = h @ Wm2[:,0] + bm2[0]; gate = sigmoid(y0) ----
  const float4* h4 = (const float4*)myh;
  float y0 = bm2[0];
  for (int kc = 0; kc < 24; kc++) {
    float4 hq = h4[kc];
    int k = kc * 4;
    y0 = fmaf(hq.x, Wm2[(k + 0) * 129], y0);
    y0 = fmaf(hq.y, Wm2[(k + 1) * 129], y0);
    y0 = fmaf(hq.z, Wm2[(k + 2) * 129], y0);
    y0 = fmaf(hq.w, Wm2[(k + 3) * 129], y0);
  }
  float gate = 1.f / (1.f + __expf(-y0));

  float* s1  = ws + O_S1;
  float* m4s = ws + O_M4S;
  unsigned* m2k = (unsigned*)ws + O_M2K;
  unsigned* m3k = (unsigned*)ws + O_M3K;
  unsigned* deg = (unsigned*)ws + O_DEG;

  // ---- f chunks: f_c = gate * (h @ Wm2[:, 1+32c : 33+32c] + bm2[...]) ; scatter ----
  for (int c = 0; c < 4; c++) {
    float f[32];
    #pragma unroll
    for (int j = 0; j < 32; j++) f[j] = bm2[1 + c * 32 + j];
    for (int kc = 0; kc < 24; kc++) {
      float4 hq = h4[kc];
      const float* w = Wm2 + (kc * 4) * 129 + 1 + c * 32;
      accN<32>(hq.x, w + 0 * 129, f);
      accN<32>(hq.y, w + 1 * 129, f);
      accN<32>(hq.z, w + 2 * 129, f);
      accN<32>(hq.w, w + 3 * 129, f);
    }
    #pragma unroll
    for (int j = 0; j < 32; j++) f[j] *= gate;
    if (act) {
      if (c == 0) {
        #pragma unroll
        for (int j = 0; j < 32; j++) atomicAdd(&s1[dn + j], f[j]);
      } else if (c == 1) {
        #pragma unroll
        for (int j = 0; j < 32; j++) atomicMax(&m2k[dn + j], fkey(f[j]));
      } else if (c == 2) {
        #pragma unroll
        for (int j = 0; j < 32; j++) atomicMin(&m3k[dn + j], fkey(f[j]));
      } else {
        #pragma unroll
        for (int j = 0; j < 32; j++) atomicAdd(&m4s[dn + j], f[j]);
      }
    }
  }
  if (act) atomicAdd(&deg[dn >> 5], 1u);

  // ---- out_ve = gate*(h@Wc + c0) + in_ve@We[128:160] + be  (f eliminated via Wc) ----
  const float* Wc = ws + O_WC;
  const float* c0 = ws + O_C0;
  float ove[32];
  #pragma unroll
  for (int j = 0; j < 32; j++) ove[j] = 0.f;
  for (int kc = 0; kc < 24; kc++) {
    float4 hq = h4[kc];
    const float* w = Wc + (kc * 4) * 32;
    accN<32>(hq.x, w + 0 * 32, ove);
    accN<32>(hq.y, w + 1 * 32, ove);
    accN<32>(hq.z, w + 2 * 32, ove);
    accN<32>(hq.w, w + 3 * 32, ove);
  }
  #pragma unroll
  for (int j = 0; j < 32; j++) ove[j] = fmaf(gate, ove[j] + c0[j], be[j]);
  {
    const float4* v4 = (const float4*)base2;
    for (int kc = 0; kc < 8; kc++) {
      float4 vq = v4[kc];
      const float* w = We + (128 + kc * 4) * 32;
      accN<32>(vq.x, w + 0 * 32, ove);
      accN<32>(vq.y, w + 1 * 32, ove);
      accN<32>(vq.z, w + 2 * 32, ove);
      accN<32>(vq.w, w + 3 * 32, ove);
    }
  }
  if (act) {
    float4* op = (float4*)(out_ve + eoff);
    #pragma unroll
    for (int jc = 0; jc < 8; jc++) {
      float4 o;
      o.x = ove[jc * 4 + 0]; o.y = ove[jc * 4 + 1];
      o.z = ove[jc * 4 + 2]; o.w = ove[jc * 4 + 3];
      op[jc] = o;
    }
  }
}

// ---- node kernel: out_vc = concat(in_vc, s1, m2, m3, m4) @ Wr + br ----
__global__ __launch_bounds__(256) void gsmp_node_kernel(
    const float* __restrict__ in_vc, const float* __restrict__ Wr,
    const float* __restrict__ br, const float* __restrict__ ws,
    float* __restrict__ out_vc)
{
  int n = blockIdx.x * 256 + threadIdx.x;
  if (n >= N_NODES) return;
  const float* s1  = ws + O_S1;
  const float* m4s = ws + O_M4S;
  const unsigned* m2k = (const unsigned*)ws + O_M2K;
  const unsigned* m3k = (const unsigned*)ws + O_M3K;
  const unsigned* deg = (const unsigned*)ws + O_DEG;

  unsigned d = deg[n];
  bool has = d > 0;
  float invd = 1.f / (float)(has ? d : 1u);
  int nb = n * 32;

  float acc[32];
  #pragma unroll
  for (int j = 0; j < 32; j++) acc[j] = br[j];

  for (int k = 0; k < 32; k++) accN<32>(in_vc[nb + k],                      Wr + (0   + k) * 32, acc);
  for (int k = 0; k < 32; k++) accN<32>(s1[nb + k],                         Wr + (32  + k) * 32, acc);
  for (int k = 0; k < 32; k++) accN<32>(has ? fdec(m2k[nb + k]) : 0.f,      Wr + (64  + k) * 32, acc);
  for (int k = 0; k < 32; k++) accN<32>(has ? fdec(m3k[nb + k]) : 0.f,      Wr + (96  + k) * 32, acc);
  for (int k = 0; k < 32; k++) accN<32>(m4s[nb + k] * invd,                 Wr + (128 + k) * 32, acc);

  float4* op = (float4*)(out_vc + (size_t)nb);
  #pragma unroll
  for (int jc = 0; jc < 8; jc++) {
    float4 o;
    o.x = acc[jc * 4 + 0]; o.y = acc[jc * 4 + 1];
    o.z = acc[jc * 4 + 2]; o.w = acc[jc * 4 + 3];
    op[jc] = o;
  }
}

extern "C" void kernel_launch(void* const* d_in, const int* in_sizes, int n_in,
                              void* d_out, int out_size, void* d_ws, size_t ws_size,
                              hipStream_t stream) {
  // Workspace guard: if d_ws is smaller than we need, bail out cleanly instead
  // of corrupting memory (shows as absmax failure, not a harness crash).
  if (ws_size < WS_BYTES) return;

  const float* in_vc = (const float*)d_in[0];
  const float* in_ve = (const float*)d_in[1];
  const int*   src   = (const int*)d_in[2];
  const int*   dst   = (const int*)d_in[3];
  const float* Wm1   = (const float*)d_in[4];
  const float* bm1   = (const float*)d_in[5];
  const float* Wm2   = (const float*)d_in[6];
  const float* bm2   = (const float*)d_in[7];
  const float* Wr    = (const float*)d_in[8];
  const float* br    = (const float*)d_in[9];
  const float* We    = (const float*)d_in[10];
  const float* be    = (const float*)d_in[11];

  float* ws     = (float*)d_ws;
  float* out_vc = (float*)d_out;
  float* out_ve = out_vc + (size_t)N_NODES * 32;

  // init accumulators: [s1 | m4s | m2k | deg] = 0 ; m3k = 0xFFFFFFFF
  hipMemsetAsync(ws + O_S1, 0, (size_t)(O_M3K - O_S1) * 4, stream);
  hipMemsetAsync(ws + O_M3K, 0xFF, (size_t)(N_NODES * 32) * 4, stream);

  gsmp_make_wc<<<13, 256, 0, stream>>>(Wm2, bm2, We, ws);
  gsmp_edge_kernel<<<N_EDGES / EB, EB, 0, stream>>>(
      in_vc, in_ve, src, dst, Wm1, bm1, Wm2, bm2, We, be, ws, out_ve);
  gsmp_node_kernel<<<(N_NODES + 255) / 256, 256, 0, stream>>>(
      in_vc, Wr, br, ws, out_vc);
}